// Round 1
// baseline (156.270 us; speedup 1.0000x reference)
//
#include <hip/hip_runtime.h>
#include <math.h>

#define KC 32      // components
#define DD 256     // dims
#define QQ 16      // rank
#define NPTS 4096
#define LOG2PI_F 1.8378770664093453f

// ws layout (float offsets)
#define OFF_LHAT   0          // [K][Q][D]  Lhat^T = (Psi^-1 Lambda)^T, layout [k][q][d]
#define OFF_V      131072     // [K][D]     psi_inv
#define OFF_W      139264     // [K][D]     psi_inv * mu
#define OFF_MINV   147456     // [K][Q][Q]  M^-1
#define OFF_U      155648     // [K][Q]     u_kq = sum_d Lhat[k][q][d]*mu[k][d]
#define OFF_LOGC   156160     // [K]        log_pi - 0.5*(D*log2pi + logdet C)
#define OFF_CK     156192     // [K]        sum_d psi_inv*mu^2

// ---------------- Kernel 1: per-component precompute (32 blocks x 256 thr) ----
__global__ __launch_bounds__(256) void precompute_kernel(
    const float* __restrict__ log_pi, const float* __restrict__ mu,
    const float* __restrict__ Lambda, const float* __restrict__ log_psi,
    float* __restrict__ ws)
{
    const int k = blockIdx.x;
    const int tid = threadIdx.x;

    __shared__ __align__(16) float sLamT[QQ * DD];   // [q][d]
    __shared__ __align__(16) float sLhatT[QQ * DD];  // [q][d]
    __shared__ __align__(16) float sMu[DD];
    __shared__ float sM[QQ * (QQ + 1)];              // 16x17 (lower Cholesky in place)
    __shared__ float sY[QQ * (QQ + 1)];              // L^-1
    __shared__ float sPart[8];
    __shared__ float sScal[2];                       // sumLogPsi, ck

    const int d = tid;  // exactly D threads
    float Psi  = expf(log_psi[k * DD + d]) + 1.1e-5f;   // exp(log_psi)+1e-6 then +1e-5 jitter
    float vinv = 1.0f / Psi;
    float mud  = mu[k * DD + d];
    float wv   = vinv * mud;
    ws[OFF_V + k * DD + d] = vinv;
    ws[OFF_W + k * DD + d] = wv;
    sMu[d] = mud;
    float logPsi = logf(Psi);
    float ckp = wv * mud;

    // load Lambda row d (16 floats)
    float lam[QQ];
    const float4* lrow = reinterpret_cast<const float4*>(Lambda + (size_t)(k * DD + d) * QQ);
#pragma unroll
    for (int i = 0; i < 4; ++i) {
        float4 t = lrow[i];
        lam[4 * i + 0] = t.x; lam[4 * i + 1] = t.y;
        lam[4 * i + 2] = t.z; lam[4 * i + 3] = t.w;
    }
#pragma unroll
    for (int q = 0; q < QQ; ++q) {
        float lh = lam[q] * vinv;
        sLamT[q * DD + d]  = lam[q];
        sLhatT[q * DD + d] = lh;
        ws[OFF_LHAT + (k * QQ + q) * DD + d] = lh;   // coalesced per q
    }

    // block reduce sum(logPsi), sum(v*mu^2)
    float r0 = logPsi, r1 = ckp;
#pragma unroll
    for (int off = 32; off >= 1; off >>= 1) {
        r0 += __shfl_down(r0, off);
        r1 += __shfl_down(r1, off);
    }
    int wave = tid >> 6;
    if ((tid & 63) == 0) { sPart[wave] = r0; sPart[4 + wave] = r1; }
    __syncthreads();
    if (tid == 0) {
        sScal[0] = sPart[0] + sPart[1] + sPart[2] + sPart[3];
        sScal[1] = sPart[4] + sPart[5] + sPart[6] + sPart[7];
    }

    // A = Lhat^T Lam (over d); M = I + A
    {
        int q = tid >> 4, r = tid & 15;
        const float4* aq = reinterpret_cast<const float4*>(sLhatT + q * DD);
        const float4* br = reinterpret_cast<const float4*>(sLamT + r * DD);
        float s = 0.f;
#pragma unroll
        for (int i = 0; i < DD / 4; ++i) {
            float4 a = aq[i], b = br[i];
            s += a.x * b.x + a.y * b.y + a.z * b.z + a.w * b.w;
        }
        sM[q * (QQ + 1) + r] = s + (q == r ? 1.0f : 0.0f);
    }
    // u[q] = <Lhat[q], mu>
    if (tid < QQ) {
        const float4* aq = reinterpret_cast<const float4*>(sLhatT + tid * DD);
        const float4* bm = reinterpret_cast<const float4*>(sMu);
        float s = 0.f;
#pragma unroll
        for (int i = 0; i < DD / 4; ++i) {
            float4 a = aq[i], b = bm[i];
            s += a.x * b.x + a.y * b.y + a.z * b.z + a.w * b.w;
        }
        ws[OFF_U + k * QQ + tid] = s;
    }
    __syncthreads();

    // cooperative Cholesky of sM (lower, in place), 16x16
    for (int j = 0; j < QQ; ++j) {
        if (tid == 0) sM[j * (QQ + 1) + j] = sqrtf(sM[j * (QQ + 1) + j]);
        __syncthreads();
        if (tid > j && tid < QQ) sM[tid * (QQ + 1) + j] /= sM[j * (QQ + 1) + j];
        __syncthreads();
        {
            int r = tid >> 4, c = tid & 15;
            if (c > j && r >= c)
                sM[r * (QQ + 1) + c] -= sM[r * (QQ + 1) + j] * sM[c * (QQ + 1) + j];
        }
        __syncthreads();
    }

    // Y = L^-1 (column per thread, fully unrolled so y[] stays in registers)
    if (tid < QQ) {
        float y[QQ];
#pragma unroll
        for (int j = 0; j < QQ; ++j) {
            float s = (j == tid) ? 1.0f : 0.0f;
#pragma unroll
            for (int i = 0; i < QQ; ++i) {
                if (i < j) s -= sM[j * (QQ + 1) + i] * y[i];
            }
            y[j] = s / sM[j * (QQ + 1) + j];
        }
#pragma unroll
        for (int j = 0; j < QQ; ++j) sY[j * (QQ + 1) + tid] = y[j];
    }
    __syncthreads();

    // Minv = Y^T Y
    {
        int q = tid >> 4, r = tid & 15;
        float s = 0.f;
#pragma unroll
        for (int j = 0; j < QQ; ++j) s += sY[j * (QQ + 1) + q] * sY[j * (QQ + 1) + r];
        ws[OFF_MINV + k * QQ * QQ + tid] = s;
    }
    if (tid == 0) {
        float logdetM = 0.f;
#pragma unroll
        for (int j = 0; j < QQ; ++j) logdetM += logf(sM[j * (QQ + 1) + j]);
        logdetM *= 2.0f;
        float logdet = sScal[0] + logdetM;   // logdet C = sum log Psi + logdet M
        ws[OFF_LOGC + k] = log_pi[k] - 0.5f * ((float)DD * LOG2PI_F + logdet);
        ws[OFF_CK + k] = sScal[1];
    }
}

// ---------------- Kernel 2: main GEMM + epilogue ------------------------------
// grid (N/32, K/2), block 256. Block: 32 rows of X vs 2 components (32 q-cols).
#define SXS 260   // padded row stride (floats) -> 2-way bank aliasing only
__global__ __launch_bounds__(256) void main_kernel(
    const float* __restrict__ X, const float* __restrict__ ws,
    float* __restrict__ out)
{
    const int tid = threadIdx.x;
    const int n0 = blockIdx.x * 32;
    const int k0 = blockIdx.y * 2;

    __shared__ __align__(16) float sX[32 * SXS];
    __shared__ __align__(16) float sL[32 * SXS];
    __shared__ __align__(16) float sT[32 * 36];
    __shared__ __align__(16) float sV[2 * DD];
    __shared__ __align__(16) float sW[2 * DD];
    __shared__ __align__(16) float sMinv[2 * DD];
    __shared__ float sU[32];
    __shared__ float sC[4];   // logc0, logc1, ck0, ck1

    {   // stage X tile (32x256) and Lhat rows (32x256), coalesced float4
        const float4* gx = reinterpret_cast<const float4*>(X + (size_t)n0 * DD);
        const float4* gl = reinterpret_cast<const float4*>(ws + OFF_LHAT + (size_t)k0 * QQ * DD);
#pragma unroll
        for (int i = 0; i < 8; ++i) {
            int f = tid + i * 256;           // float4 index
            int row = f >> 6, d4 = f & 63;
            *reinterpret_cast<float4*>(&sX[row * SXS + d4 * 4]) = gx[f];
        }
#pragma unroll
        for (int i = 0; i < 8; ++i) {
            int f = tid + i * 256;
            int row = f >> 6, d4 = f & 63;
            *reinterpret_cast<float4*>(&sL[row * SXS + d4 * 4]) = gl[f];
        }
        for (int i = tid; i < 512; i += 256) {
            sV[i]    = ws[OFF_V    + k0 * DD + i];
            sW[i]    = ws[OFF_W    + k0 * DD + i];
            sMinv[i] = ws[OFF_MINV + k0 * QQ * QQ + i];
        }
        if (tid < 32) sU[tid] = ws[OFF_U + k0 * QQ + tid];
        if (tid < 2) { sC[tid] = ws[OFF_LOGC + k0 + tid]; sC[2 + tid] = ws[OFF_CK + k0 + tid]; }
    }
    __syncthreads();

    // 2x2 register tile: rows {ty, ty+16}, cols {tx, tx+16}
    const int tx = tid & 15, ty = tid >> 4;
    float acc00 = 0.f, acc01 = 0.f, acc10 = 0.f, acc11 = 0.f;
    const float* xr0 = sX + ty * SXS;
    const float* xr1 = sX + (ty + 16) * SXS;
    const float* lc0 = sL + tx * SXS;
    const float* lc1 = sL + (tx + 16) * SXS;
#pragma unroll 4
    for (int i = 0; i < 64; ++i) {
        float4 a0 = *reinterpret_cast<const float4*>(xr0 + i * 4);
        float4 a1 = *reinterpret_cast<const float4*>(xr1 + i * 4);
        float4 b0 = *reinterpret_cast<const float4*>(lc0 + i * 4);
        float4 b1 = *reinterpret_cast<const float4*>(lc1 + i * 4);
        acc00 += a0.x * b0.x + a0.y * b0.y + a0.z * b0.z + a0.w * b0.w;
        acc01 += a0.x * b1.x + a0.y * b1.y + a0.z * b1.z + a0.w * b1.w;
        acc10 += a1.x * b0.x + a1.y * b0.y + a1.z * b0.z + a1.w * b0.w;
        acc11 += a1.x * b1.x + a1.y * b1.y + a1.z * b1.z + a1.w * b1.w;
    }
    // t = t' - u
    sT[ty * 36 + tx]             = acc00 - sU[tx];
    sT[ty * 36 + tx + 16]        = acc01 - sU[tx + 16];
    sT[(ty + 16) * 36 + tx]      = acc10 - sU[tx];
    sT[(ty + 16) * 36 + tx + 16] = acc11 - sU[tx + 16];
    __syncthreads();

    // epilogue: 8 threads per row (2 kk x 4 lane-slices)
    {
        const int row = tid >> 3, sub = tid & 7, kk = sub >> 2, l4 = sub & 3;
        const float4* xr = reinterpret_cast<const float4*>(sX + row * SXS);
        const float4* vv = reinterpret_cast<const float4*>(sV + kk * DD);
        const float4* wwp = reinterpret_cast<const float4*>(sW + kk * DD);
        float qx = 0.f, sx = 0.f;
#pragma unroll
        for (int i = 0; i < 16; ++i) {
            float4 x = xr[l4 * 16 + i];
            float4 a = vv[l4 * 16 + i];
            float4 b = wwp[l4 * 16 + i];
            qx += a.x * x.x * x.x + a.y * x.y * x.y + a.z * x.z * x.z + a.w * x.w * x.w;
            sx += b.x * x.x + b.y * x.y + b.z * x.z + b.w * x.w;
        }
        const float* trow = sT + row * 36 + kk * 16;
        float t[QQ];
#pragma unroll
        for (int i = 0; i < QQ; ++i) t[i] = trow[i];
        float corr = 0.f;
#pragma unroll
        for (int qi = 0; qi < 4; ++qi) {
            int q = l4 * 4 + qi;
            const float* mr = sMinv + kk * DD + q * QQ;
            float tq = trow[q];          // LDS read (runtime index) — avoids register-array spill
            float inner = 0.f;
#pragma unroll
            for (int r = 0; r < QQ; ++r) inner += mr[r] * t[r];
            corr += tq * inner;
        }
        qx   += __shfl_xor(qx, 1);   qx   += __shfl_xor(qx, 2);
        sx   += __shfl_xor(sx, 1);   sx   += __shfl_xor(sx, 2);
        corr += __shfl_xor(corr, 1); corr += __shfl_xor(corr, 2);
        if (l4 == 0) {
            float maha0 = qx - 2.0f * sx + sC[2 + kk];
            float maha  = maha0 - corr;
            out[(size_t)(n0 + row) * KC + k0 + kk] = sC[kk] - 0.5f * maha;
        }
    }
}

// ---------------- Kernel 3: row logsumexp + normalize (in place) --------------
__global__ __launch_bounds__(256) void norm_kernel(float* __restrict__ out)
{
    int n = blockIdx.x * 256 + threadIdx.x;
    float4 v[8];
    const float4* rp = reinterpret_cast<const float4*>(out + (size_t)n * KC);
    float m = -INFINITY;
#pragma unroll
    for (int i = 0; i < 8; ++i) {
        v[i] = rp[i];
        m = fmaxf(m, fmaxf(fmaxf(v[i].x, v[i].y), fmaxf(v[i].z, v[i].w)));
    }
    float s = 0.f;
#pragma unroll
    for (int i = 0; i < 8; ++i)
        s += expf(v[i].x - m) + expf(v[i].y - m) + expf(v[i].z - m) + expf(v[i].w - m);
    float lse = m + logf(s);
    float4* wp = reinterpret_cast<float4*>(out + (size_t)n * KC);
#pragma unroll
    for (int i = 0; i < 8; ++i) {
        float4 o;
        o.x = v[i].x - lse; o.y = v[i].y - lse; o.z = v[i].z - lse; o.w = v[i].w - lse;
        wp[i] = o;
    }
    out[(size_t)NPTS * KC + n] = lse;
}

extern "C" void kernel_launch(void* const* d_in, const int* in_sizes, int n_in,
                              void* d_out, int out_size, void* d_ws, size_t ws_size,
                              hipStream_t stream)
{
    (void)in_sizes; (void)n_in; (void)out_size; (void)ws_size;
    const float* X       = (const float*)d_in[0];
    const float* log_pi  = (const float*)d_in[1];
    const float* mu      = (const float*)d_in[2];
    const float* Lambda  = (const float*)d_in[3];
    const float* log_psi = (const float*)d_in[4];
    float* out = (float*)d_out;
    float* ws  = (float*)d_ws;   // needs ~625 KB

    precompute_kernel<<<dim3(KC), dim3(256), 0, stream>>>(log_pi, mu, Lambda, log_psi, ws);
    main_kernel<<<dim3(NPTS / 32, KC / 2), dim3(256), 0, stream>>>(X, ws, out);
    norm_kernel<<<dim3(NPTS / 256), dim3(256), 0, stream>>>(out);
}

// Round 2
// 104.254 us; speedup vs baseline: 1.4989x; 1.4989x over previous
//
#include <hip/hip_runtime.h>
#include <math.h>

#define KC 32      // components
#define DD 256     // dims
#define QQ 16      // rank
#define NPTS 4096
#define LOG2PI_F 1.8378770664093453f

typedef unsigned short ushort_t;

// ws layout (float offsets)
#define OFF_VW     0          // [K][D][2]  interleaved (psi_inv, psi_inv*mu)
#define OFF_MINV   16384      // [K][Q][Q]  M^-1 row-major
#define OFF_U      24576      // [K*Q]      u = Lhat . mu
#define OFF_LOGC   25088      // [K]        log_pi - 0.5*(D*log2pi + logdet C + ck)
#define OFF_HB     25152      // ushort region: [512][256] bf16 Lhat rows (col-major over q-comp, d contiguous)

__device__ __forceinline__ ushort_t f2bf(float f) {
    union { float f; unsigned int u; } c; c.f = f;
    unsigned int u = c.u;
    return (ushort_t)((u + 0x7FFFu + ((u >> 16) & 1u)) >> 16);   // RNE
}

// ---------------- Kernel 1: per-component precompute (32 blocks x 256 thr) ----
__global__ __launch_bounds__(256) void precompute_kernel(
    const float* __restrict__ log_pi, const float* __restrict__ mu,
    const float* __restrict__ Lambda, const float* __restrict__ log_psi,
    float* __restrict__ ws)
{
    const int k = blockIdx.x;
    const int tid = threadIdx.x;
    ushort_t* hb = (ushort_t*)(ws + OFF_HB);

    __shared__ __align__(16) float sLamT[QQ * DD];   // [q][d]
    __shared__ __align__(16) float sLhatT[QQ * DD];  // [q][d]
    __shared__ __align__(16) float sMu[DD];
    __shared__ float sM[QQ * (QQ + 1)];              // 16x17 (lower Cholesky in place)
    __shared__ float sY[QQ * (QQ + 1)];              // L^-1
    __shared__ float sPart[8];
    __shared__ float sScal[2];                       // sumLogPsi, ck

    const int d = tid;  // exactly D threads
    float Psi  = expf(log_psi[k * DD + d]) + 1.1e-5f;   // exp(log_psi)+1e-6 then +1e-5 jitter
    float vinv = 1.0f / Psi;
    float mud  = mu[k * DD + d];
    float wv   = vinv * mud;
    reinterpret_cast<float2*>(ws + OFF_VW + k * 2 * DD)[d] = make_float2(vinv, wv);
    sMu[d] = mud;
    float logPsi = logf(Psi);
    float ckp = wv * mud;

    // load Lambda row d (16 floats)
    float lam[QQ];
    const float4* lrow = reinterpret_cast<const float4*>(Lambda + (size_t)(k * DD + d) * QQ);
#pragma unroll
    for (int i = 0; i < 4; ++i) {
        float4 t = lrow[i];
        lam[4 * i + 0] = t.x; lam[4 * i + 1] = t.y;
        lam[4 * i + 2] = t.z; lam[4 * i + 3] = t.w;
    }
#pragma unroll
    for (int q = 0; q < QQ; ++q) {
        float lh = lam[q] * vinv;
        sLamT[q * DD + d]  = lam[q];
        sLhatT[q * DD + d] = lh;
        hb[(k * QQ + q) * DD + d] = f2bf(lh);        // coalesced per q
    }

    // block reduce sum(logPsi), sum(v*mu^2)
    float r0 = logPsi, r1 = ckp;
#pragma unroll
    for (int off = 32; off >= 1; off >>= 1) {
        r0 += __shfl_down(r0, off);
        r1 += __shfl_down(r1, off);
    }
    int wave = tid >> 6;
    if ((tid & 63) == 0) { sPart[wave] = r0; sPart[4 + wave] = r1; }
    __syncthreads();
    if (tid == 0) {
        sScal[0] = sPart[0] + sPart[1] + sPart[2] + sPart[3];
        sScal[1] = sPart[4] + sPart[5] + sPart[6] + sPart[7];
    }

    // A = Lhat^T Lam (over d); M = I + A
    {
        int q = tid >> 4, r = tid & 15;
        const float4* aq = reinterpret_cast<const float4*>(sLhatT + q * DD);
        const float4* br = reinterpret_cast<const float4*>(sLamT + r * DD);
        float s = 0.f;
#pragma unroll
        for (int i = 0; i < DD / 4; ++i) {
            float4 a = aq[i], b = br[i];
            s += a.x * b.x + a.y * b.y + a.z * b.z + a.w * b.w;
        }
        sM[q * (QQ + 1) + r] = s + (q == r ? 1.0f : 0.0f);
    }
    // u[q] = <Lhat[q], mu>
    if (tid < QQ) {
        const float4* aq = reinterpret_cast<const float4*>(sLhatT + tid * DD);
        const float4* bm = reinterpret_cast<const float4*>(sMu);
        float s = 0.f;
#pragma unroll
        for (int i = 0; i < DD / 4; ++i) {
            float4 a = aq[i], b = bm[i];
            s += a.x * b.x + a.y * b.y + a.z * b.z + a.w * b.w;
        }
        ws[OFF_U + k * QQ + tid] = s;
    }
    __syncthreads();

    // cooperative Cholesky of sM (lower, in place), 16x16
    for (int j = 0; j < QQ; ++j) {
        if (tid == 0) sM[j * (QQ + 1) + j] = sqrtf(sM[j * (QQ + 1) + j]);
        __syncthreads();
        if (tid > j && tid < QQ) sM[tid * (QQ + 1) + j] /= sM[j * (QQ + 1) + j];
        __syncthreads();
        {
            int r = tid >> 4, c = tid & 15;
            if (c > j && r >= c)
                sM[r * (QQ + 1) + c] -= sM[r * (QQ + 1) + j] * sM[c * (QQ + 1) + j];
        }
        __syncthreads();
    }

    // Y = L^-1 (column per thread, fully unrolled so y[] stays in registers)
    if (tid < QQ) {
        float y[QQ];
#pragma unroll
        for (int j = 0; j < QQ; ++j) {
            float s = (j == tid) ? 1.0f : 0.0f;
#pragma unroll
            for (int i = 0; i < QQ; ++i) {
                if (i < j) s -= sM[j * (QQ + 1) + i] * y[i];
            }
            y[j] = s / sM[j * (QQ + 1) + j];
        }
#pragma unroll
        for (int j = 0; j < QQ; ++j) sY[j * (QQ + 1) + tid] = y[j];
    }
    __syncthreads();

    // Minv = Y^T Y
    {
        int q = tid >> 4, r = tid & 15;
        float s = 0.f;
#pragma unroll
        for (int j = 0; j < QQ; ++j) s += sY[j * (QQ + 1) + q] * sY[j * (QQ + 1) + r];
        ws[OFF_MINV + k * QQ * QQ + tid] = s;
    }
    if (tid == 0) {
        float logdetM = 0.f;
#pragma unroll
        for (int j = 0; j < QQ; ++j) logdetM += logf(sM[j * (QQ + 1) + j]);
        logdetM *= 2.0f;
        float logdet = sScal[0] + logdetM;   // logdet C = sum log Psi + logdet M
        // fold ck into the constant: out = logc2 - 0.5*(qx - 2 sx - corr)
        ws[OFF_LOGC + k] = log_pi[k] - 0.5f * ((float)DD * LOG2PI_F + logdet) - 0.5f * sScal[1];
    }
}

// ---------------- Kernel 2: fused MFMA GEMM + epilogue + logsumexp ------------
// grid 256 blocks, 256 threads. Block: 16 rows of X x ALL 32 components.
#define SXF 260   // fp32 X row stride (floats)  -> 2-way bank aliasing max
#define SXH 264   // bf16 X row stride (ushorts) -> 2-way for b128 frag reads
#define STS 516   // t-matrix row stride (floats)
#define SRS 36    // log-resp row stride

using short8 = __attribute__((ext_vector_type(8))) short;   // 8 bf16 (4 VGPRs)
using f32x4  = __attribute__((ext_vector_type(4))) float;   // 4 fp32 acc

__global__ __launch_bounds__(256) void main_kernel(
    const float* __restrict__ X, const float* __restrict__ ws,
    float* __restrict__ out)
{
    const int tid  = threadIdx.x;
    const int n0   = blockIdx.x * 16;
    const int lane = tid & 63;
    const int wave = tid >> 6;
    const ushort_t* hB = (const ushort_t*)(ws + OFF_HB);

    __shared__ __align__(16) float    sXf[16 * SXF];
    __shared__ __align__(16) ushort_t sXh[16 * SXH];
    __shared__ __align__(16) float    sT[16 * STS];
    __shared__ float sU[512];
    __shared__ float sR[16 * SRS];
    __shared__ float sLse[16];

    // ---- stage X tile (16x256): fp32 copy + bf16 copy ----
    {
        const float4* gx = reinterpret_cast<const float4*>(X + (size_t)n0 * DD);
#pragma unroll
        for (int i = 0; i < 4; ++i) {
            int f = tid + i * 256;          // float4 index, 1024 total
            int row = f >> 6, d4 = f & 63;
            float4 v = gx[f];
            *reinterpret_cast<float4*>(sXf + row * SXF + d4 * 4) = v;
            ushort4 h = make_ushort4(f2bf(v.x), f2bf(v.y), f2bf(v.z), f2bf(v.w));
            *reinterpret_cast<ushort4*>(sXh + row * SXH + d4 * 4) = h;
        }
        sU[tid]       = ws[OFF_U + tid];
        sU[tid + 256] = ws[OFF_U + 256 + tid];
    }
    __syncthreads();

    // ---- MFMA: t' = X . Lhat^T  (16 rows x 512 cols, K=256) ----
    // wave w handles cols [w*128, w*128+128) = 8 col-tiles of 16.
    {
        const int arow = lane & 15;          // A row m / C col within tile
        const int quad = lane >> 4;          // k-quad
        f32x4 acc[8];
#pragma unroll
        for (int t = 0; t < 8; ++t) acc[t] = (f32x4){0.f, 0.f, 0.f, 0.f};

        const ushort_t* sA = sXh + arow * SXH + quad * 8;
        const ushort_t* gB = hB + (size_t)(wave * 128 + arow) * DD + quad * 8;
#pragma unroll
        for (int ks = 0; ks < 8; ++ks) {
            short8 a = *reinterpret_cast<const short8*>(sA + ks * 32);
#pragma unroll
            for (int t = 0; t < 8; ++t) {
                short8 b = *reinterpret_cast<const short8*>(gB + t * 16 * DD + ks * 32);
                acc[t] = __builtin_amdgcn_mfma_f32_16x16x32_bf16(a, b, acc[t], 0, 0, 0);
            }
        }
        // C/D layout: col = lane&15 (within tile), row = quad*4 + reg
#pragma unroll
        for (int t = 0; t < 8; ++t) {
            int cc = wave * 128 + t * 16 + arow;
#pragma unroll
            for (int r = 0; r < 4; ++r) {
                int rr = quad * 4 + r;
                sT[rr * STS + cc] = acc[t][r] - sU[cc];   // t = Lhat^T x - u
            }
        }
    }
    __syncthreads();

    // ---- epilogue: per (row, comp) log-resp; thread -> row=tid&15, comps {c0, c0+16}
    {
        const int row = tid & 15, c0 = tid >> 4;
        const float4* xr = reinterpret_cast<const float4*>(sXf + row * SXF);
#pragma unroll
        for (int ci = 0; ci < 2; ++ci) {
            const int c = c0 + ci * 16;
            const float4* vw = reinterpret_cast<const float4*>(ws + OFF_VW + c * 2 * DD);
            float qx = 0.f, sx = 0.f;
#pragma unroll 8
            for (int i = 0; i < 64; ++i) {
                float4 x = xr[i];
                float4 a = vw[2 * i];        // v0 w0 v1 w1
                float4 b = vw[2 * i + 1];    // v2 w2 v3 w3
                qx += a.x * x.x * x.x + a.z * x.y * x.y + b.x * x.z * x.z + b.z * x.w * x.w;
                sx += a.y * x.x + a.w * x.y + b.y * x.z + b.w * x.w;
            }
            float t[QQ];
            const float* trow = sT + row * STS + c * 16;
#pragma unroll
            for (int q = 0; q < QQ; ++q) t[q] = trow[q];
            const float4* mi = reinterpret_cast<const float4*>(ws + OFF_MINV + c * 256);
            float corr = 0.f;
#pragma unroll
            for (int q = 0; q < QQ; ++q) {
                float4 m0 = mi[q * 4], m1 = mi[q * 4 + 1], m2 = mi[q * 4 + 2], m3 = mi[q * 4 + 3];
                float inner = m0.x * t[0] + m0.y * t[1] + m0.z * t[2] + m0.w * t[3]
                            + m1.x * t[4] + m1.y * t[5] + m1.z * t[6] + m1.w * t[7]
                            + m2.x * t[8] + m2.y * t[9] + m2.z * t[10] + m2.w * t[11]
                            + m3.x * t[12] + m3.y * t[13] + m3.z * t[14] + m3.w * t[15];
                corr += t[q] * inner;
            }
            float logc2 = ws[OFF_LOGC + c];
            sR[row * SRS + c] = logc2 - 0.5f * (qx - 2.0f * sx - corr);
        }
    }
    __syncthreads();

    // ---- logsumexp per row + outputs ----
    if (tid < 16) {
        float m = -INFINITY;
#pragma unroll
        for (int c = 0; c < KC; ++c) m = fmaxf(m, sR[tid * SRS + c]);
        float s = 0.f;
#pragma unroll
        for (int c = 0; c < KC; ++c) s += expf(sR[tid * SRS + c] - m);
        float lse = m + logf(s);
        sLse[tid] = lse;
        out[(size_t)NPTS * KC + n0 + tid] = lse;
    }
    __syncthreads();
    if (tid < 128) {
        int r = tid >> 3, i = tid & 7;
        float lse = sLse[r];
        float4 v = *reinterpret_cast<const float4*>(sR + r * SRS + i * 4);
        float4 o = make_float4(v.x - lse, v.y - lse, v.z - lse, v.w - lse);
        *reinterpret_cast<float4*>(out + (size_t)(n0 + r) * KC + i * 4) = o;
    }
}

extern "C" void kernel_launch(void* const* d_in, const int* in_sizes, int n_in,
                              void* d_out, int out_size, void* d_ws, size_t ws_size,
                              hipStream_t stream)
{
    (void)in_sizes; (void)n_in; (void)out_size; (void)ws_size;
    const float* X       = (const float*)d_in[0];
    const float* log_pi  = (const float*)d_in[1];
    const float* mu      = (const float*)d_in[2];
    const float* Lambda  = (const float*)d_in[3];
    const float* log_psi = (const float*)d_in[4];
    float* out = (float*)d_out;
    float* ws  = (float*)d_ws;   // ~363 KB used

    precompute_kernel<<<dim3(KC), dim3(256), 0, stream>>>(log_pi, mu, Lambda, log_psi, ws);
    main_kernel<<<dim3(NPTS / 16), dim3(256), 0, stream>>>(X, ws, out);
}